// Round 5
// baseline (414.763 us; speedup 1.0000x reference)
//
#include <hip/hip_runtime.h>
#include <hip/hip_bf16.h>
#include <math.h>

typedef __hip_bfloat16 bf16;
typedef __bf16 bf16x8 __attribute__((ext_vector_type(8)));
typedef float f32x4 __attribute__((ext_vector_type(4)));

static __device__ __forceinline__ float b2f(bf16 v) { return __bfloat162float(v); }
static __device__ __forceinline__ bf16 f2b(float v) { return __float2bfloat16(v); }
static __device__ __forceinline__ unsigned int packbf(float a, float b)
{
    bf16 ha = f2b(a), hb = f2b(b);
    unsigned short ua, ub;
    __builtin_memcpy(&ua, &ha, 2);
    __builtin_memcpy(&ub, &hb, 2);
    return (unsigned int)ua | ((unsigned int)ub << 16);
}

#define TK 32

// ---------------------------------------------------------------------------
// Generic MFMA GEMM:  D[m][n] = sum_k A[m][k]*Bt[n][k] (+bias[m]) (*(1+cs[n]))
// Tile 128x64, BK=32. M%128==0, N%64==0, K%32==0.
// ---------------------------------------------------------------------------
template <typename TOUT>
__global__ __launch_bounds__(256) void gemm_bt(
    const bf16* __restrict__ A, size_t sA,
    const bf16* __restrict__ Bt, size_t sB,
    const float* __restrict__ bias, size_t sBias,
    const float* __restrict__ colScale, size_t sCS,
    TOUT* __restrict__ D, size_t sD,
    int M, int N, int Kd, int transStore)
{
    A  += (size_t)blockIdx.z * sA;
    Bt += (size_t)blockIdx.z * sB;
    D  += (size_t)blockIdx.z * sD;
    if (bias)     bias     += (size_t)blockIdx.z * sBias;
    if (colScale) colScale += (size_t)blockIdx.z * sCS;

    const int m0 = blockIdx.y * 128, n0 = blockIdx.x * 64;
    const int t = threadIdx.x, wv = t >> 6, lane = t & 63;
    const int lr = lane & 15, quad = lane >> 4;

    __shared__ bf16 lA[128][TK + 8];
    __shared__ bf16 lB[64][TK + 8];

    f32x4 acc[2][4];
#pragma unroll
    for (int i = 0; i < 2; ++i)
#pragma unroll
        for (int j = 0; j < 4; ++j) acc[i][j] = (f32x4){0.f, 0.f, 0.f, 0.f};

    const int arow = t >> 1, acol = (t & 1) * 16;
    const int brow = t >> 2, bcol = (t & 3) * 8;
    const bf16* aptr = A  + (size_t)(m0 + arow) * Kd + acol;
    const bf16* bptr = Bt + (size_t)(n0 + brow) * Kd + bcol;

    for (int k0 = 0; k0 < Kd; k0 += TK) {
        __syncthreads();
        uint4 a0 = *(const uint4*)(aptr + k0);
        uint4 a1 = *(const uint4*)(aptr + k0 + 8);
        uint4 b0 = *(const uint4*)(bptr + k0);
        *(uint4*)(&lA[arow][acol])     = a0;
        *(uint4*)(&lA[arow][acol + 8]) = a1;
        *(uint4*)(&lB[brow][bcol])     = b0;
        __syncthreads();

        bf16x8 af0 = *(const bf16x8*)(&lA[wv * 32 + lr][quad * 8]);
        bf16x8 af1 = *(const bf16x8*)(&lA[wv * 32 + 16 + lr][quad * 8]);
#pragma unroll
        for (int j = 0; j < 4; ++j) {
            bf16x8 bfj = *(const bf16x8*)(&lB[j * 16 + lr][quad * 8]);
            acc[0][j] = __builtin_amdgcn_mfma_f32_16x16x32_bf16(af0, bfj, acc[0][j], 0, 0, 0);
            acc[1][j] = __builtin_amdgcn_mfma_f32_16x16x32_bf16(af1, bfj, acc[1][j], 0, 0, 0);
        }
    }

#pragma unroll
    for (int i = 0; i < 2; ++i) {
        const int mb = m0 + wv * 32 + i * 16 + quad * 4;
#pragma unroll
        for (int r = 0; r < 4; ++r) {
            const int mm = mb + r;
            const float bvv = bias ? bias[mm] : 0.f;
#pragma unroll
            for (int j = 0; j < 4; ++j) {
                const int nn = n0 + j * 16 + lr;
                float v = acc[i][j][r] + bvv;
                if (colScale) v *= (1.f + colScale[nn]);
                const size_t o = transStore ? ((size_t)nn * M + mm)
                                            : ((size_t)mm * N + nn);
                if constexpr (__is_same(TOUT, float)) D[o] = v;
                else                                  D[o] = f2b(v);
            }
        }
    }
}

// ---------------------------------------------------------------------------
// Dual-product GEMM: D = A1*B1t + A2*B2t. Used with (G_hi,G_lo)x(Wk,Wk) and
// (Wq,Wq)x(Tt_hi,Tt_lo) for ~fp32-accurate products through bf16 MFMA.
// Output: hi/lo bf16 pair (Dhi,Dlo) or single fp32 (Df).
// ---------------------------------------------------------------------------
__global__ __launch_bounds__(256) void gemm_bt2(
    const bf16* __restrict__ A1, const bf16* __restrict__ A2, size_t sA,
    const bf16* __restrict__ B1, const bf16* __restrict__ B2, size_t sB,
    bf16* __restrict__ Dhi, bf16* __restrict__ Dlo,
    float* __restrict__ Df, size_t sD,
    int M, int N, int Kd, int transStore)
{
    A1 += (size_t)blockIdx.z * sA;
    A2 += (size_t)blockIdx.z * sA;
    B1 += (size_t)blockIdx.z * sB;
    B2 += (size_t)blockIdx.z * sB;

    const int m0 = blockIdx.y * 128, n0 = blockIdx.x * 64;
    const int t = threadIdx.x, wv = t >> 6, lane = t & 63;
    const int lr = lane & 15, quad = lane >> 4;

    __shared__ bf16 lA1[128][TK + 8];
    __shared__ bf16 lA2[128][TK + 8];
    __shared__ bf16 lB1[64][TK + 8];
    __shared__ bf16 lB2[64][TK + 8];

    f32x4 acc[2][4];
#pragma unroll
    for (int i = 0; i < 2; ++i)
#pragma unroll
        for (int j = 0; j < 4; ++j) acc[i][j] = (f32x4){0.f, 0.f, 0.f, 0.f};

    const int arow = t >> 1, acol = (t & 1) * 16;
    const int brow = t >> 2, bcol = (t & 3) * 8;
    const size_t aoff = (size_t)(m0 + arow) * Kd + acol;
    const size_t boff = (size_t)(n0 + brow) * Kd + bcol;

    for (int k0 = 0; k0 < Kd; k0 += TK) {
        __syncthreads();
        uint4 a10 = *(const uint4*)(A1 + aoff + k0);
        uint4 a11 = *(const uint4*)(A1 + aoff + k0 + 8);
        uint4 a20 = *(const uint4*)(A2 + aoff + k0);
        uint4 a21 = *(const uint4*)(A2 + aoff + k0 + 8);
        uint4 b1  = *(const uint4*)(B1 + boff + k0);
        uint4 b2  = *(const uint4*)(B2 + boff + k0);
        *(uint4*)(&lA1[arow][acol])     = a10;
        *(uint4*)(&lA1[arow][acol + 8]) = a11;
        *(uint4*)(&lA2[arow][acol])     = a20;
        *(uint4*)(&lA2[arow][acol + 8]) = a21;
        *(uint4*)(&lB1[brow][bcol])     = b1;
        *(uint4*)(&lB2[brow][bcol])     = b2;
        __syncthreads();

        bf16x8 a1f0 = *(const bf16x8*)(&lA1[wv * 32 + lr][quad * 8]);
        bf16x8 a1f1 = *(const bf16x8*)(&lA1[wv * 32 + 16 + lr][quad * 8]);
        bf16x8 a2f0 = *(const bf16x8*)(&lA2[wv * 32 + lr][quad * 8]);
        bf16x8 a2f1 = *(const bf16x8*)(&lA2[wv * 32 + 16 + lr][quad * 8]);
#pragma unroll
        for (int j = 0; j < 4; ++j) {
            bf16x8 b1j = *(const bf16x8*)(&lB1[j * 16 + lr][quad * 8]);
            bf16x8 b2j = *(const bf16x8*)(&lB2[j * 16 + lr][quad * 8]);
            acc[0][j] = __builtin_amdgcn_mfma_f32_16x16x32_bf16(a1f0, b1j, acc[0][j], 0, 0, 0);
            acc[0][j] = __builtin_amdgcn_mfma_f32_16x16x32_bf16(a2f0, b2j, acc[0][j], 0, 0, 0);
            acc[1][j] = __builtin_amdgcn_mfma_f32_16x16x32_bf16(a1f1, b1j, acc[1][j], 0, 0, 0);
            acc[1][j] = __builtin_amdgcn_mfma_f32_16x16x32_bf16(a2f1, b2j, acc[1][j], 0, 0, 0);
        }
    }

#pragma unroll
    for (int i = 0; i < 2; ++i) {
        const int mb = m0 + wv * 32 + i * 16 + quad * 4;
#pragma unroll
        for (int r = 0; r < 4; ++r) {
            const int mm = mb + r;
#pragma unroll
            for (int j = 0; j < 4; ++j) {
                const int nn = n0 + j * 16 + lr;
                const float v = acc[i][j][r];
                const size_t o = (transStore ? ((size_t)nn * M + mm)
                                             : ((size_t)mm * N + nn))
                                 + (size_t)blockIdx.z * sD;
                if (Df) {
                    Df[o] = v;
                } else {
                    bf16 h = f2b(v);
                    Dhi[o] = h;
                    Dlo[o] = f2b(v - b2f(h));
                }
            }
        }
    }
}

// ---------------------------------------------------------------------------
// Gram partials: part[s][b][c1][c2] = sum_{n in chunk s} x[c1][n]*x[c2][n]
// Upper-triangle tiles only (20 of 32), split-K=4. x fp32 -> bf16 staging.
// Grid (20, 4, 8).
// ---------------------------------------------------------------------------
__global__ __launch_bounds__(256) void gemm_gram(
    const float* __restrict__ x, float* __restrict__ part)
{
    const int li = blockIdx.x, s = blockIdx.y, b = blockIdx.z;
    int mi, ni;
    if (li < 8)       { mi = 0; ni = li; }
    else if (li < 14) { mi = 1; ni = li - 6; }
    else if (li < 18) { mi = 2; ni = li - 10; }
    else              { mi = 3; ni = li - 12; }
    const int m0 = mi * 128, n0 = ni * 64;
    const float* xb = x + (size_t)b * 512 * 4096;

    const int t = threadIdx.x, wv = t >> 6, lane = t & 63;
    const int lr = lane & 15, quad = lane >> 4;

    __shared__ bf16 lA[128][TK + 8];
    __shared__ bf16 lB[64][TK + 8];
    unsigned int* lAu = (unsigned int*)lA;
    unsigned int* lBu = (unsigned int*)lB;

    f32x4 acc[2][4];
#pragma unroll
    for (int i = 0; i < 2; ++i)
#pragma unroll
        for (int j = 0; j < 4; ++j) acc[i][j] = (f32x4){0.f, 0.f, 0.f, 0.f};

    const int arow = t >> 1, acol = (t & 1) * 16;
    const int brow = t >> 2, bcol = (t & 3) * 8;
    const float* aptr = xb + (size_t)(m0 + arow) * 4096 + acol;
    const float* bptr = xb + (size_t)(n0 + brow) * 4096 + bcol;

    const int kBeg = s * 1024, kEnd = kBeg + 1024;
    for (int k0 = kBeg; k0 < kEnd; k0 += TK) {
        __syncthreads();
        float4 af[4], bf[2];
#pragma unroll
        for (int q = 0; q < 4; ++q) af[q] = *(const float4*)(aptr + k0 + q * 4);
#pragma unroll
        for (int q = 0; q < 2; ++q) bf[q] = *(const float4*)(bptr + k0 + q * 4);
        {
            unsigned int w[8];
            const float* fa = (const float*)af;
#pragma unroll
            for (int q = 0; q < 8; ++q) w[q] = packbf(fa[2 * q], fa[2 * q + 1]);
            *(uint4*)&lAu[arow * 20 + acol / 2]     = *(uint4*)&w[0];
            *(uint4*)&lAu[arow * 20 + acol / 2 + 4] = *(uint4*)&w[4];
            unsigned int v[4];
            const float* fb = (const float*)bf;
#pragma unroll
            for (int q = 0; q < 4; ++q) v[q] = packbf(fb[2 * q], fb[2 * q + 1]);
            *(uint4*)&lBu[brow * 20 + bcol / 2] = *(uint4*)&v[0];
        }
        __syncthreads();

        bf16x8 af0 = *(const bf16x8*)(&lA[wv * 32 + lr][quad * 8]);
        bf16x8 af1 = *(const bf16x8*)(&lA[wv * 32 + 16 + lr][quad * 8]);
#pragma unroll
        for (int j = 0; j < 4; ++j) {
            bf16x8 bfj = *(const bf16x8*)(&lB[j * 16 + lr][quad * 8]);
            acc[0][j] = __builtin_amdgcn_mfma_f32_16x16x32_bf16(af0, bfj, acc[0][j], 0, 0, 0);
            acc[1][j] = __builtin_amdgcn_mfma_f32_16x16x32_bf16(af1, bfj, acc[1][j], 0, 0, 0);
        }
    }

    float* dst = part + ((size_t)(s * 8 + b)) * 262144;
#pragma unroll
    for (int i = 0; i < 2; ++i) {
        const int mb = m0 + wv * 32 + i * 16 + quad * 4;
#pragma unroll
        for (int r = 0; r < 4; ++r) {
            const int mm = mb + r;
#pragma unroll
            for (int j = 0; j < 4; ++j)
                dst[(size_t)mm * 512 + n0 + j * 16 + lr] = acc[i][j][r];
        }
    }
}

// ---------------------------------------------------------------------------
// G = modulated Gram from Gx partials (mirrored upper tiles) + rank-1 terms.
// G[c1][c2] = (1+s1)(1+s2)Gx + (1+s1)sh2*xs1 + sh1(1+s2)*xs2 + 4096*sh1*sh2
// Output hi/lo bf16 pair.
// ---------------------------------------------------------------------------
__global__ void k_fixG(const float* __restrict__ part, const float* __restrict__ ss,
                       const float* __restrict__ xsum,
                       bf16* __restrict__ Ghi, bf16* __restrict__ Glo)
{
    const int e = blockIdx.x * 256 + threadIdx.x;   // < 8*512*512
    const int b = e >> 18, rem = e & 262143;
    const int c1 = rem >> 9, c2 = rem & 511;
    const int stored = (c2 >> 6) >= 2 * (c1 >> 7);
    const size_t src = stored ? ((size_t)c1 * 512 + c2) : ((size_t)c2 * 512 + c1);
    float gx = 0.f;
#pragma unroll
    for (int s = 0; s < 4; ++s)
        gx += part[((size_t)(s * 8 + b)) * 262144 + src];
    const float s1 = ss[b * 1024 + c1], sh1 = ss[b * 1024 + 512 + c1];
    const float s2 = ss[b * 1024 + c2], sh2 = ss[b * 1024 + 512 + c2];
    const float xs1 = xsum[b * 512 + c1], xs2 = xsum[b * 512 + c2];
    const float g = (1.f + s1) * (1.f + s2) * gx + (1.f + s1) * sh2 * xs1
                    + sh1 * (1.f + s2) * xs2 + 4096.f * sh1 * sh2;
    const bf16 h = f2b(g);
    Ghi[e] = h;
    Glo[e] = f2b(g - b2f(h));
}

// ---------------------------------------------------------------------------
// Final GEMM: out[o][n] = sum_c W3p[o][c] * x[c][n] + bias2[o]   (fp32 out)
// x staged natural->LDS-transposed with packed-b32 swizzle (<=2-way banks).
// Grid (64, 4, 8).
// ---------------------------------------------------------------------------
__global__ __launch_bounds__(256) void gemm_final(
    const bf16* __restrict__ W3p, const float* __restrict__ x,
    const float* __restrict__ bias2, float* __restrict__ out)
{
    const int b = blockIdx.z;
    const int m0 = blockIdx.y * 128, n0 = blockIdx.x * 64;
    const bf16* A = W3p + (size_t)b * 262144;
    const float* xb = x + (size_t)b * 512 * 4096;
    bias2 += b * 512;
    out += (size_t)b * 2097152;

    const int t = threadIdx.x, wv = t >> 6, lane = t & 63;
    const int lr = lane & 15, quad = lane >> 4;

    __shared__ bf16 lA[128][TK + 8];
    __shared__ unsigned int lBu[64 * 20];

    f32x4 acc[2][4];
#pragma unroll
    for (int i = 0; i < 2; ++i)
#pragma unroll
        for (int j = 0; j < 4; ++j) acc[i][j] = (f32x4){0.f, 0.f, 0.f, 0.f};

    const int arow = t >> 1, acol = (t & 1) * 16;
    const bf16* aptr = A + (size_t)(m0 + arow) * 512 + acol;
    const int kp = t >> 4, nc = (t & 15) * 4;          // k-pair 0..15, n-chunk
    const int grp = kp >> 2, wIn = kp & 3;
    const float* xp0 = xb + (size_t)(2 * kp) * 4096 + n0 + nc;

    for (int k0 = 0; k0 < 512; k0 += TK) {
        __syncthreads();
        uint4 a0 = *(const uint4*)(aptr + k0);
        uint4 a1 = *(const uint4*)(aptr + k0 + 8);
        const float4 r0 = *(const float4*)(xp0 + (size_t)k0 * 4096);
        const float4 r1 = *(const float4*)(xp0 + (size_t)k0 * 4096 + 4096);
        *(uint4*)(&lA[arow][acol])     = a0;
        *(uint4*)(&lA[arow][acol + 8]) = a1;
        {
            const float v0[4] = {r0.x, r0.y, r0.z, r0.w};
            const float v1[4] = {r1.x, r1.y, r1.z, r1.w};
#pragma unroll
            for (int i = 0; i < 4; ++i) {
                const int n = nc + i;
                lBu[n * 20 + (((grp ^ ((n >> 3) & 3)) << 2) | wIn)] =
                    packbf(v0[i], v1[i]);
            }
        }
        __syncthreads();

        bf16x8 af0 = *(const bf16x8*)(&lA[wv * 32 + lr][quad * 8]);
        bf16x8 af1 = *(const bf16x8*)(&lA[wv * 32 + 16 + lr][quad * 8]);
#pragma unroll
        for (int j = 0; j < 4; ++j) {
            const int n = j * 16 + lr;
            bf16x8 bfj = *(const bf16x8*)(&lBu[n * 20 + ((quad ^ ((n >> 3) & 3)) << 2)]);
            acc[0][j] = __builtin_amdgcn_mfma_f32_16x16x32_bf16(af0, bfj, acc[0][j], 0, 0, 0);
            acc[1][j] = __builtin_amdgcn_mfma_f32_16x16x32_bf16(af1, bfj, acc[1][j], 0, 0, 0);
        }
    }

#pragma unroll
    for (int i = 0; i < 2; ++i) {
        const int mb = m0 + wv * 32 + i * 16 + quad * 4;
#pragma unroll
        for (int r = 0; r < 4; ++r) {
            const int mm = mb + r;
            const float bvv = bias2[mm];
#pragma unroll
            for (int j = 0; j < 4; ++j)
                out[(size_t)mm * 4096 + n0 + j * 16 + lr] = acc[i][j][r] + bvv;
        }
    }
}

// ---------------------------------------------------------------------------
// Small kernels
// ---------------------------------------------------------------------------

__global__ void k_silu(const float* __restrict__ in, float* __restrict__ out, int n)
{
    int i = blockIdx.x * 256 + threadIdx.x;
    if (i < n) {
        float v = in[i];
        out[i] = v / (1.f + expf(-v));
    }
}

__global__ void k_xmean(const float* __restrict__ x, float* __restrict__ xsum)
{
    const int bc = blockIdx.x;
    const float4* p = (const float4*)(x + (size_t)bc * 4096);
    float s = 0.f;
#pragma unroll
    for (int r = 0; r < 4; ++r) {
        float4 v = p[threadIdx.x + r * 256];
        s += v.x + v.y + v.z + v.w;
    }
    for (int off = 32; off; off >>= 1) s += __shfl_down(s, off);
    __shared__ float red[4];
    if ((threadIdx.x & 63) == 0) red[threadIdx.x >> 6] = s;
    __syncthreads();
    if (threadIdx.x == 0)
        xsum[bc] = red[0] + red[1] + red[2] + red[3];
}

__global__ void k_smallgemm(const float* __restrict__ in, const float* __restrict__ W,
                            const float* __restrict__ bias, float* __restrict__ out,
                            int Mrows, int O, int Kd, int act)
{
    const int gw = (blockIdx.x * 256 + threadIdx.x) >> 6;
    const int lane = threadIdx.x & 63;
    if (gw >= Mrows * O) return;
    const int m = gw / O, o = gw - m * O;
    float s = 0.f;
    for (int k = lane; k < Kd; k += 64)
        s += in[m * Kd + k] * W[(size_t)o * Kd + k];
    for (int off = 32; off; off >>= 1) s += __shfl_down(s, off);
    if (lane == 0) {
        s += bias[o];
        if (act) s = s / (1.f + expf(-s));
        out[m * O + o] = s;
    }
}

__global__ void k_mlp1(const float* __restrict__ ss, const float* __restrict__ xsum,
                       const float* __restrict__ tp, const float* __restrict__ w_m1,
                       const float* __restrict__ b_m1, float* __restrict__ hidden)
{
    const int gw = (blockIdx.x * 256 + threadIdx.x) >> 6;
    const int lane = threadIdx.x & 63;
    if (gw >= 8 * 1024) return;
    const int m = gw >> 10, o = gw & 1023;
    float s = 0.f;
    for (int k = lane; k < 1024; k += 64) {
        float pv;
        if (k < 512) pv = (1.f + ss[m * 1024 + k]) * (xsum[m * 512 + k] * (1.f / 4096.f))
                          + ss[m * 1024 + 512 + k];
        else         pv = tp[m * 512 + k - 512];
        s += pv * w_m1[(size_t)o * 1024 + k];
    }
    for (int off = 32; off; off >>= 1) s += __shfl_down(s, off);
    if (lane == 0) {
        s += b_m1[o];
        hidden[m * 1024 + o] = s / (1.f + expf(-s));
    }
}

__global__ void k_topk(const float* __restrict__ prompt, int* __restrict__ idx)
{
    __shared__ float v[512];
    __shared__ int sel[512];
    const int b = blockIdx.x, c = threadIdx.x;
    v[c] = prompt[b * 512 + c];
    __syncthreads();
    const float mv = v[c];
    int rank = 0;
    for (int j = 0; j < 512; ++j) {
        float o = v[j];
        rank += (o > mv) || (o == mv && j < c);
    }
    sel[c] = (rank < 256) ? 1 : 0;
    __syncthreads();
    if (rank < 256) {
        int pos = 0;
        for (int j = 0; j < c; ++j) pos += sel[j];
        idx[b * 256 + pos] = c;
    }
}

// gathers: wq_g/wk_g [j][c], wo_g [o][j], wvT_g [c][l]=wv[id[l]][c], biases
__global__ void k_gather(const int* __restrict__ idx,
                         const float* __restrict__ wq, const float* __restrict__ bq,
                         const float* __restrict__ wk, const float* __restrict__ bk,
                         const float* __restrict__ wv, const float* __restrict__ bv,
                         const float* __restrict__ wo,
                         bf16* __restrict__ wq_g, bf16* __restrict__ wk_g,
                         bf16* __restrict__ wo_g, bf16* __restrict__ wvT_g,
                         float* __restrict__ bq_g, float* __restrict__ bk_g,
                         float* __restrict__ bv_g)
{
    const int b = blockIdx.z;
    const int* id = idx + b * 256;
    const int tid = blockIdx.x * 256 + threadIdx.x;  // < 131072
    {
        const int j = tid >> 9, c = tid & 511;
        const int ch = id[j];
        wq_g[(size_t)b * 131072 + tid] = f2b(wq[ch * 512 + c]);
        wk_g[(size_t)b * 131072 + tid] = f2b(wk[ch * 512 + c]);
    }
    {
        const int o = tid >> 8, j = tid & 255;
        wo_g[(size_t)b * 131072 + tid] = f2b(wo[o * 512 + id[j]]);
    }
    {
        const int c = tid >> 8, l = tid & 255;
        wvT_g[(size_t)b * 131072 + tid] = f2b(wv[id[l] * 512 + c]);
    }
    if (tid < 256) {
        const int ch = id[tid];
        bq_g[b * 256 + tid] = bq[ch];
        bk_g[b * 256 + tid] = bk[ch];
        bv_g[b * 256 + tid] = bv[ch];
    }
}

// qh[b][j]=sum_c Wq_g[j,c]*hsum[c], kh likewise; hsum=(1+s)*xsum+4096*sh
__global__ void k_qhkh(const bf16* __restrict__ wq_g, const bf16* __restrict__ wk_g,
                       const float* __restrict__ ss, const float* __restrict__ xsum,
                       float* __restrict__ qh, float* __restrict__ kh)
{
    const int gw = (blockIdx.x * 256 + threadIdx.x) >> 6;  // < 4096
    const int lane = threadIdx.x & 63;
    const int b = gw >> 9, rem = gw & 511;
    const int which = rem >> 8, j = rem & 255;
    const bf16* W = which ? wk_g : wq_g;
    float s = 0.f;
    for (int c = lane; c < 512; c += 64) {
        const float hs = (1.f + ss[b * 1024 + c]) * xsum[b * 512 + c]
                         + 4096.f * ss[b * 1024 + 512 + c];
        s += b2f(W[(size_t)b * 131072 + j * 512 + c]) * hs;
    }
    for (int off = 32; off; off >>= 1) s += __shfl_down(s, off);
    if (lane == 0) (which ? kh : qh)[b * 256 + j] = s;
}

// vsh[b][l] = sum_c wv[id[l]][c] * shift[c]
__global__ void k_vsh(const float* __restrict__ wv, const int* __restrict__ idx,
                      const float* __restrict__ ss, float* __restrict__ vsh)
{
    const int gw = (blockIdx.x * 256 + threadIdx.x) >> 6;  // < 2048
    const int lane = threadIdx.x & 63;
    const int b = gw >> 8, l = gw & 255;
    const int ch = idx[b * 256 + l];
    float s = 0.f;
    for (int c = lane; c < 512; c += 64)
        s += wv[ch * 512 + c] * ss[b * 1024 + 512 + c];
    for (int off = 32; off; off >>= 1) s += __shfl_down(s, off);
    if (lane == 0) vsh[b * 256 + l] = s;
}

// bias2[b][o] = bo[o] + sum_l W2[o,l]*(vsh[l]+bv_g[l])
__global__ void k_bias2(const bf16* __restrict__ W2, const float* __restrict__ vsh,
                        const float* __restrict__ bv_g, const float* __restrict__ bo,
                        float* __restrict__ bias2)
{
    const int gw = (blockIdx.x * 256 + threadIdx.x) >> 6;  // < 4096
    const int lane = threadIdx.x & 63;
    const int b = gw >> 9, o = gw & 511;
    float s = 0.f;
    for (int l = lane; l < 256; l += 64)
        s += b2f(W2[(size_t)b * 131072 + o * 256 + l]) * (vsh[b * 256 + l] + bv_g[b * 256 + l]);
    for (int off = 32; off; off >>= 1) s += __shfl_down(s, off);
    if (lane == 0) bias2[b * 512 + o] = s + bo[o];
}

// softmax over l of (S + rank-1 bias terms)/16, write P transposed
__global__ void k_softmax2(const float* __restrict__ S, const float* __restrict__ qh,
                           const float* __restrict__ kh, const float* __restrict__ bq_g,
                           const float* __restrict__ bk_g, bf16* __restrict__ Pt)
{
    const int row = blockIdx.x;          // b*256 + j
    const int b = row >> 8, j = row & 255;
    const int t = threadIdx.x;
    const int lane = t & 63, wv = t >> 6;
    __shared__ float redm[4], reds[4];
    float v = S[(size_t)row * 256 + t]
            + bq_g[b * 256 + j] * kh[b * 256 + t]
            + bk_g[b * 256 + t] * qh[b * 256 + j]
            + 4096.f * bq_g[b * 256 + j] * bk_g[b * 256 + t];
    v *= 0.0625f;
    float m = v;
    for (int off = 32; off; off >>= 1) m = fmaxf(m, __shfl_down(m, off));
    if (lane == 0) redm[wv] = m;
    __syncthreads();
    m = fmaxf(fmaxf(redm[0], redm[1]), fmaxf(redm[2], redm[3]));
    const float e = __expf(v - m);
    float s = e;
    for (int off = 32; off; off >>= 1) s += __shfl_down(s, off);
    if (lane == 0) reds[wv] = s;
    __syncthreads();
    s = reds[0] + reds[1] + reds[2] + reds[3];
    Pt[(size_t)b * 65536 + (size_t)t * 256 + j] = f2b(e / s);
}

// ---------------------------------------------------------------------------

extern "C" void kernel_launch(void* const* d_in, const int* in_sizes, int n_in,
                              void* d_out, int out_size, void* d_ws, size_t ws_size,
                              hipStream_t stream)
{
    const float* x        = (const float*)d_in[0];
    const float* temb     = (const float*)d_in[1];
    const float* w_affine = (const float*)d_in[2];
    const float* b_affine = (const float*)d_in[3];
    const float* w_tp     = (const float*)d_in[4];
    const float* b_tp     = (const float*)d_in[5];
    const float* w_m1     = (const float*)d_in[6];
    const float* b_m1     = (const float*)d_in[7];
    const float* w_m2     = (const float*)d_in[8];
    const float* b_m2     = (const float*)d_in[9];
    const float* wq       = (const float*)d_in[10];
    const float* bq       = (const float*)d_in[11];
    const float* wk       = (const float*)d_in[12];
    const float* bk       = (const float*)d_in[13];
    const float* wv       = (const float*)d_in[14];
    const float* bv       = (const float*)d_in[15];
    const float* wo       = (const float*)d_in[16];
    const float* bo       = (const float*)d_in[17];
    float* out = (float*)d_out;

    char* ws = (char*)d_ws;
    size_t off = 0;
    auto alloc = [&](size_t bytes) -> char* {
        char* p = ws + off;
        off += (bytes + 255) & ~(size_t)255;
        return p;
    };

    float* temb_act = (float*)alloc(4096 * 4);
    float* ssb      = (float*)alloc(8192 * 4);
    float* tp       = (float*)alloc(4096 * 4);
    float* xsum     = (float*)alloc(4096 * 4);
    float* hidden   = (float*)alloc(8192 * 4);
    float* prompt   = (float*)alloc(4096 * 4);
    int*   idx      = (int*)alloc(2048 * 4);
    float* part   = (float*)alloc((size_t)4 * 8 * 512 * 512 * 4);   // 33.5 MB
    bf16*  Ghi    = (bf16*)alloc((size_t)8 * 512 * 512 * 2);
    bf16*  Glo    = (bf16*)alloc((size_t)8 * 512 * 512 * 2);
    bf16*  wq_g   = (bf16*)alloc((size_t)8 * 256 * 512 * 2);
    bf16*  wk_g   = (bf16*)alloc((size_t)8 * 256 * 512 * 2);
    bf16*  wo_g   = (bf16*)alloc((size_t)8 * 512 * 256 * 2);
    bf16*  wvT_g  = (bf16*)alloc((size_t)8 * 512 * 256 * 2);
    float* bq_g   = (float*)alloc(8 * 256 * 4);
    float* bk_g   = (float*)alloc(8 * 256 * 4);
    float* bv_g   = (float*)alloc(8 * 256 * 4);
    bf16*  Tt_hi  = (bf16*)alloc((size_t)8 * 256 * 512 * 2);
    bf16*  Tt_lo  = (bf16*)alloc((size_t)8 * 256 * 512 * 2);
    float* Sbuf   = (float*)alloc((size_t)8 * 256 * 256 * 4);
    float* qh     = (float*)alloc(2048 * 4);
    float* kh     = (float*)alloc(2048 * 4);
    float* vsh    = (float*)alloc(2048 * 4);
    bf16*  Pt     = (bf16*)alloc((size_t)8 * 256 * 256 * 2);
    bf16*  W2     = (bf16*)alloc((size_t)8 * 512 * 256 * 2);
    float* bias2  = (float*)alloc(4096 * 4);
    bf16*  W3p    = (bf16*)alloc((size_t)8 * 512 * 512 * 2);
    (void)ws_size; (void)n_in; (void)in_sizes; (void)out_size;

    // --- Gram of raw x (independent; biggest independent chain first)
    gemm_gram<<<dim3(20, 4, 8), 256, 0, stream>>>(x, part);
    // --- prologue
    k_silu<<<16, 256, 0, stream>>>(temb, temb_act, 4096);
    k_xmean<<<4096, 256, 0, stream>>>(x, xsum);
    k_smallgemm<<<2048, 256, 0, stream>>>(temb_act, w_affine, b_affine, ssb, 8, 1024, 512, 0);
    k_smallgemm<<<1024, 256, 0, stream>>>(temb_act, w_tp, b_tp, tp, 8, 512, 512, 0);
    k_mlp1<<<2048, 256, 0, stream>>>(ssb, xsum, tp, w_m1, b_m1, hidden);
    k_smallgemm<<<1024, 256, 0, stream>>>(hidden, w_m2, b_m2, prompt, 8, 512, 1024, 0);
    k_topk<<<8, 512, 0, stream>>>(prompt, idx);
    k_gather<<<dim3(512, 1, 8), 256, 0, stream>>>(idx, wq, bq, wk, bk, wv, bv, wo,
                                                  wq_g, wk_g, wo_g, wvT_g,
                                                  bq_g, bk_g, bv_g);
    // --- G (modulated Gram, hi/lo)
    k_fixG<<<8192, 256, 0, stream>>>(part, ssb, xsum, Ghi, Glo);
    // --- T^t = (G * Wk_g^T)^T, hi/lo   [l][c1]
    gemm_bt2<<<dim3(4, 4, 8), 256, 0, stream>>>(Ghi, Glo, 262144, wk_g, wk_g, 131072,
                                                Tt_hi, Tt_lo, nullptr, 131072,
                                                512, 256, 512, 1);
    // --- S = Wq_g * T  (fp32)
    gemm_bt2<<<dim3(4, 2, 8), 256, 0, stream>>>(wq_g, wq_g, 131072, Tt_hi, Tt_lo, 131072,
                                                nullptr, nullptr, Sbuf, 65536,
                                                256, 256, 512, 0);
    // --- rank-1 bias vectors + softmax -> P^T
    k_qhkh<<<1024, 256, 0, stream>>>(wq_g, wk_g, ssb, xsum, qh, kh);
    k_vsh<<<512, 256, 0, stream>>>(wv, idx, ssb, vsh);
    k_softmax2<<<2048, 256, 0, stream>>>(Sbuf, qh, kh, bq_g, bk_g, Pt);
    // --- W2 = wo_g * P   [o][l]
    gemm_bt<bf16><<<dim3(4, 4, 8), 256, 0, stream>>>(wo_g, 131072, Pt, 65536,
                                                     nullptr, 0, nullptr, 0,
                                                     W2, 131072, 512, 256, 256, 0);
    k_bias2<<<1024, 256, 0, stream>>>(W2, vsh, bv_g, bo, bias2);
    // --- W3' = (W2 * Wv_g) * diag(1+scale)   [o][c]
    gemm_bt<bf16><<<dim3(8, 4, 8), 256, 0, stream>>>(W2, 131072, wvT_g, 131072,
                                                     nullptr, 0, ssb, 1024,
                                                     W3p, 262144, 512, 512, 256, 0);
    // --- out = W3' * x + bias2
    gemm_final<<<dim3(64, 4, 8), 256, 0, stream>>>(W3p, x, bias2, out);
}